// Round 2
// baseline (1405.906 us; speedup 1.0000x reference)
//
#include <hip/hip_runtime.h>

// HierarchicalRouter: B=32768 tokens, H=4096, 16 groups x 16 experts.
// Inputs fp32: hidden[B,H], group_w[16,H], expert_w[16,16,H].
// Output fp32 (concat): [B,256] all_expert_logits, [B] selected_experts, [B] expert_weights.
//
// fp32 end-to-end (argmax fidelity).
// R2 change: kill the 1.75x overfetch + 16B-granular gathers. Hidden is staged
// through LDS in [64 tokens x 64 cols] chunks with fully-coalesced global loads
// (256B contiguous per 16-thread group, every 64B line consumed by one inst).
// LDS chunk is column-major padded (At[c][65]) -> 2-way banks on both write and
// read (free). Double-buffered, T14 split: issue next load -> compute -> LDS
// write -> one barrier. Reduce arrays alias the staging buffer (43 KB total,
// 2 blocks/CU kept).

constexpr int Btok = 32768;
constexpr int Hdim = 4096;
constexpr int Gn   = 16;
constexpr int EPGn = 16;
constexpr int En   = 256;
constexpr int BK   = 64;           // columns per staged chunk
constexpr int NCH  = Hdim / BK;    // 64 chunks
constexpr int TILE = 1024;         // tokens per kernel-2 tile

// column-major padded chunk: buf in {0,1}, c in [0,64), r in [0,64)
#define AT(b,c,r) smem[(b)*(BK*65) + (c)*65 + (r)]

__global__ __launch_bounds__(1024, 8) void k_group(
    const float* __restrict__ hidden, const float* __restrict__ gw,
    unsigned char* __restrict__ gsel)
{
  __shared__ float smem[8704];   // 34.8 KB: At[2][64][65] (8320) | part[8][64][17] (8704)
  float (*part)[64][Gn + 1] = reinterpret_cast<float (*)[64][Gn + 1]>(smem);

  const int lane = threadIdx.x & 63;
  const int wq = __builtin_amdgcn_readfirstlane((int)(threadIdx.x >> 6)); // 0..15
  const int cw = wq * 4;                   // this wave's 4 columns of each chunk
  const int r  = threadIdx.x >> 4;         // staging row 0..63
  const int c0 = (threadIdx.x & 15) << 2;  // staging col base 0..60
  const int tbase = blockIdx.x * 64;

  const float* gptr = hidden + (size_t)(tbase + r) * Hdim + c0;

  // prologue: chunk 0 -> buf 0
  {
    const float4 v = *reinterpret_cast<const float4*>(gptr);
    AT(0, c0 + 0, r) = v.x; AT(0, c0 + 1, r) = v.y;
    AT(0, c0 + 2, r) = v.z; AT(0, c0 + 3, r) = v.w;
  }
  __syncthreads();

  float acc[Gn];
#pragma unroll
  for (int g = 0; g < Gn; ++g) acc[g] = 0.f;

#pragma unroll 2
  for (int k = 0; k < NCH; ++k) {
    const int buf = k & 1;
    const bool more = (k + 1 < NCH);
    float4 p;
    if (more) p = *reinterpret_cast<const float4*>(gptr + (k + 1) * BK); // issue early

    const float a0 = AT(buf, cw + 0, lane);
    const float a1 = AT(buf, cw + 1, lane);
    const float a2 = AT(buf, cw + 2, lane);
    const float a3 = AT(buf, cw + 3, lane);
    const float* wk = gw + k * BK + cw;      // wave-uniform -> s_load
#pragma unroll
    for (int g = 0; g < Gn; ++g) {
      const float* wg = wk + (size_t)g * Hdim;
      acc[g] += a0 * wg[0] + a1 * wg[1] + a2 * wg[2] + a3 * wg[3];
    }

    if (more) {   // write-late: buf^1 reads finished before prev barrier
      AT(buf ^ 1, c0 + 0, r) = p.x; AT(buf ^ 1, c0 + 1, r) = p.y;
      AT(buf ^ 1, c0 + 2, r) = p.z; AT(buf ^ 1, c0 + 3, r) = p.w;
    }
    __syncthreads();
  }

  // Two-round cross-wave reduce (aliases smem; all At reads done before barrier).
  if (wq >= 8) {
#pragma unroll
    for (int g = 0; g < Gn; ++g) part[wq - 8][lane][g] = acc[g];
  }
  __syncthreads();
  if (wq < 8) {
#pragma unroll
    for (int g = 0; g < Gn; ++g) part[wq][lane][g] += acc[g];
  }
  __syncthreads();

  // thread t -> (tok = t>>4, g = t&15): final 8-way sum + 16-lane argmax.
  const int tok = threadIdx.x >> 4;
  const int g   = threadIdx.x & 15;
  float v = 0.f;
#pragma unroll
  for (int s = 0; s < 8; ++s) v += part[s][tok][g];

  int bi = g;
#pragma unroll
  for (int off = 8; off; off >>= 1) {
    float v2 = __shfl_xor(v, off);
    int   i2 = __shfl_xor(bi, off);
    if (v2 > v || (v2 == v && i2 < bi)) { v = v2; bi = i2; }  // first-max
  }
  if (g == 0) gsel[tbase + tok] = (unsigned char)bi;
}

__global__ __launch_bounds__(1024, 8) void k_expert(
    const float* __restrict__ hidden, const float* __restrict__ ew,
    const unsigned char* __restrict__ gsel,
    float* __restrict__ out0,   // [B,256]
    float* __restrict__ out1,   // [B] selected expert (as float)
    float* __restrict__ out2)   // [B] expert weight
{
  const int g = blockIdx.x;              // 0..15
  const int tbase = blockIdx.y * TILE;

  __shared__ float smem[8704];           // At[2][64][65] | part[8][64][17]
  __shared__ int   list[TILE];
  __shared__ int   cnt;
  __shared__ float lrow[64][EPGn + 1];
  float (*part)[64][EPGn + 1] = reinterpret_cast<float (*)[64][EPGn + 1]>(smem);

  if (threadIdx.x == 0) cnt = 0;
  __syncthreads();
  for (int i = threadIdx.x; i < TILE; i += 1024) {
    if ((int)gsel[tbase + i] == g) {
      int p = atomicAdd(&cnt, 1);
      list[p] = tbase + i;
    }
  }
  __syncthreads();
  const int n = cnt;

  const int lane = threadIdx.x & 63;
  const int wq = __builtin_amdgcn_readfirstlane((int)(threadIdx.x >> 6)); // 0..15
  const int cw = wq * 4;
  const int r  = threadIdx.x >> 4;
  const int c0 = (threadIdx.x & 15) << 2;
  const float* wbase = ew + ((size_t)g * EPGn) * Hdim;

  for (int s0 = 0; s0 < n; s0 += 64) {
    const int ns = min(64, n - s0);
    // clamp dup rows for tail sub-batch: dup loads hit L1/L2, ~no HBM waste
    const int rr = (r < ns) ? r : (ns - 1);
    const float* gptr = hidden + (size_t)list[s0 + rr] * Hdim + c0;

    {
      const float4 v = *reinterpret_cast<const float4*>(gptr);
      AT(0, c0 + 0, r) = v.x; AT(0, c0 + 1, r) = v.y;
      AT(0, c0 + 2, r) = v.z; AT(0, c0 + 3, r) = v.w;
    }
    __syncthreads();

    float acc[EPGn];
#pragma unroll
    for (int e = 0; e < EPGn; ++e) acc[e] = 0.f;

#pragma unroll 2
    for (int k = 0; k < NCH; ++k) {
      const int buf = k & 1;
      const bool more = (k + 1 < NCH);
      float4 p;
      if (more) p = *reinterpret_cast<const float4*>(gptr + (k + 1) * BK);

      const float a0 = AT(buf, cw + 0, lane);
      const float a1 = AT(buf, cw + 1, lane);
      const float a2 = AT(buf, cw + 2, lane);
      const float a3 = AT(buf, cw + 3, lane);
      const float* wk = wbase + k * BK + cw;   // wave-uniform -> s_load
#pragma unroll
      for (int e = 0; e < EPGn; ++e) {
        const float* we = wk + (size_t)e * Hdim;
        acc[e] += a0 * we[0] + a1 * we[1] + a2 * we[2] + a3 * we[3];
      }

      if (more) {
        AT(buf ^ 1, c0 + 0, r) = p.x; AT(buf ^ 1, c0 + 1, r) = p.y;
        AT(buf ^ 1, c0 + 2, r) = p.z; AT(buf ^ 1, c0 + 3, r) = p.w;
      }
      __syncthreads();
    }

    if (wq >= 8) {
#pragma unroll
      for (int e = 0; e < EPGn; ++e) part[wq - 8][lane][e] = acc[e];
    }
    __syncthreads();
    if (wq < 8) {
#pragma unroll
      for (int e = 0; e < EPGn; ++e) part[wq][lane][e] += acc[e];
    }
    __syncthreads();

    // thread t -> (tk = t>>4, e = t&15): final sum + softmax + argmax.
    const int tk = threadIdx.x >> 4;
    const int e  = threadIdx.x & 15;
    float l = 0.f;
#pragma unroll
    for (int s = 0; s < 8; ++s) l += part[s][tk][e];
    lrow[tk][e] = l;   // written & read by the same 16-thread group (no barrier)

    float m = l;
#pragma unroll
    for (int off = 8; off; off >>= 1) m = fmaxf(m, __shfl_xor(m, off));
    float sum = __expf(l - m);
#pragma unroll
    for (int off = 8; off; off >>= 1) sum += __shfl_xor(sum, off);

    float v = l; int bi = e;
#pragma unroll
    for (int off = 8; off; off >>= 1) {
      float v2 = __shfl_xor(v, off);
      int   i2 = __shfl_xor(bi, off);
      if (v2 > v || (v2 == v && i2 < bi)) { v = v2; bi = i2; }  // first-max
    }
    if (e == 0 && tk < ns) {
      const int tok = list[s0 + tk];
      out1[tok] = (float)(g * EPGn + bi);
      out2[tok] = 1.f / sum;             // exp(max-max)/sum == top prob
    }

    // Write full 256-wide fp32 row: zeros except the selected group's block.
    if (tk < ns) {
      const int tok = list[s0 + tk];
      float* row = out0 + (size_t)tok * En + e * 16;
      if (e == g) {
#pragma unroll
        for (int q = 0; q < 4; ++q) {
          float4 v4;
          v4.x = lrow[tk][q * 4 + 0];
          v4.y = lrow[tk][q * 4 + 1];
          v4.z = lrow[tk][q * 4 + 2];
          v4.w = lrow[tk][q * 4 + 3];
          *reinterpret_cast<float4*>(row + q * 4) = v4;
        }
      } else {
        const float4 z = {0.f, 0.f, 0.f, 0.f};
#pragma unroll
        for (int q = 0; q < 4; ++q)
          *reinterpret_cast<float4*>(row + q * 4) = z;
      }
    }
    __syncthreads();   // protect smem/lrow before next sub-batch
  }
}

extern "C" void kernel_launch(void* const* d_in, const int* in_sizes, int n_in,
                              void* d_out, int out_size, void* d_ws, size_t ws_size,
                              hipStream_t stream) {
  const float* hidden = (const float*)d_in[0];
  const float* gw     = (const float*)d_in[1];
  const float* ew     = (const float*)d_in[2];
  float* out0 = (float*)d_out;
  unsigned char* gsel = (unsigned char*)d_ws;        // 32 KB scratch

  k_group<<<Btok / 64, 1024, 0, stream>>>(hidden, gw, gsel);

  float* out1 = out0 + (size_t)Btok * En;
  float* out2 = out1 + Btok;
  k_expert<<<dim3(Gn, Btok / TILE), 1024, 0, stream>>>(
      hidden, ew, gsel, out0, out1, out2);
}